// Round 1
// baseline (424.342 us; speedup 1.0000x reference)
//
#include <hip/hip_runtime.h>

#define NN 100000
#define NE 1600000
#define IC 128
#define HID 32

// ---------------- edge dtype detection ----------------
// If edge_index is int64, every int64-read value is in [0, NN).
// If it is int32, an int64 read combines two random indices -> >= 2^32 a.s.
__global__ void detect_kernel(const void* ei, int* flag) {
    const long long* p = (const long long*)ei;
    int ok = 1;
    for (int i = 0; i < 64; i++) {
        long long v = p[i];
        if (v < 0 || v >= NN) ok = 0;
    }
    *flag = ok;
}

__device__ __forceinline__ int edge_at(const void* ei, int i64f, long long idx) {
    return i64f ? (int)((const long long*)ei)[idx] : ((const int*)ei)[idx];
}

// ---------------- misc ----------------
__global__ void zero_kernel(int* p, int n) {
    int i = blockIdx.x * 256 + threadIdx.x;
    if (i < n) p[i] = 0;
}

// Fold w1b@w2a, b1b@w2a, w2b@w3, b2b@w3 into combined operators.
__global__ void precompute_kernel(const float* __restrict__ w1b, const float* __restrict__ b1b,
                                  const float* __restrict__ w2a, const float* __restrict__ w2b,
                                  const float* __restrict__ b2b, const float* __restrict__ w3,
                                  float* Wc, float* bc1, float* wc2, float* c0) {
    int t = threadIdx.x;           // 1024 threads
    int k = t >> 5, j = t & 31;
    float acc = 0.f;
    for (int m = 0; m < HID; m++) acc += w1b[k * HID + m] * w2a[m * HID + j];
    Wc[k * HID + j] = acc;
    if (t < 32) {
        float a = 0.f;
        for (int m = 0; m < HID; m++) a += b1b[m] * w2a[m * HID + t];
        bc1[t] = a;
    } else if (t < 64) {
        int kk = t - 32;
        float a = 0.f;
        for (int jj = 0; jj < HID; jj++) a += w2b[kk * HID + jj] * w3[jj];
        wc2[kk] = a;
    } else if (t == 64) {
        float a = 0.f;
        for (int jj = 0; jj < HID; jj++) a += b2b[jj] * w3[jj];
        *c0 = a;
    }
}

// ---------------- proj1: y1 = x @ w1a  (100000x128 @ 128x32, fp32) ----------------
// 64-node tile per block, 256 threads, each thread 2 nodes x 4 features.
__global__ __launch_bounds__(256) void proj1_kernel(const float* __restrict__ x,
                                                    const float* __restrict__ w1a,
                                                    float* __restrict__ y1) {
    __shared__ float xs[64 * 132];   // padded stride 132 (row*528B is 16B aligned, low bank conflict)
    __shared__ float ws[IC * HID];   // 16 KB
    int t = threadIdx.x;
    int base = blockIdx.x * 64;

    #pragma unroll
    for (int i = 0; i < 16; i++) ws[i * 256 + t] = w1a[i * 256 + t];

    const float4* xg = (const float4*)x;
    #pragma unroll
    for (int i = 0; i < 8; i++) {
        int fi = i * 256 + t;      // 0..2047
        int row = fi >> 5;         // 0..63
        int kq = fi & 31;          // float4 index within row
        float4 v = make_float4(0.f, 0.f, 0.f, 0.f);
        if (base + row < NN) v = xg[(base + row) * 32 + kq];
        *(float4*)&xs[row * 132 + kq * 4] = v;
    }
    __syncthreads();

    int ng = t >> 3;       // 0..31  -> node pair
    int fg = t & 7;        // 0..7   -> feature quad
    int n0 = ng * 2, n1 = n0 + 1;
    int j0 = fg * 4;
    float4 a0 = make_float4(0.f, 0.f, 0.f, 0.f);
    float4 a1 = make_float4(0.f, 0.f, 0.f, 0.f);
    #pragma unroll 8
    for (int k = 0; k < IC; k++) {
        float x0 = xs[n0 * 132 + k];
        float x1 = xs[n1 * 132 + k];
        float4 w = *(const float4*)&ws[k * HID + j0];
        a0.x += x0 * w.x; a0.y += x0 * w.y; a0.z += x0 * w.z; a0.w += x0 * w.w;
        a1.x += x1 * w.x; a1.y += x1 * w.y; a1.z += x1 * w.z; a1.w += x1 * w.w;
    }
    if (base + n0 < NN) ((float4*)y1)[(base + n0) * 8 + fg] = a0;
    if (base + n1 < NN) ((float4*)y1)[(base + n1) * 8 + fg] = a1;
}

// ---------------- CSR build ----------------
__global__ __launch_bounds__(256) void count_kernel(const void* ei, const int* flag, int* cnt) {
    int e = blockIdx.x * 256 + threadIdx.x;
    if (e >= NE) return;
    int i64f = *flag;
    int d = edge_at(ei, i64f, (long long)NE + e);
    atomicAdd(&cnt[d], 1);
}

#define SCAN_B 1024
#define NB1 98   // ceil(100000/1024)

__global__ __launch_bounds__(SCAN_B) void scan1_kernel(const int* __restrict__ cnt,
                                                       int* __restrict__ rowptr, int* __restrict__ bsums) {
    __shared__ int sh[SCAN_B];
    int t = threadIdx.x;
    int i = blockIdx.x * SCAN_B + t;
    int v = (i < NN) ? cnt[i] : 0;
    sh[t] = v;
    __syncthreads();
    for (int off = 1; off < SCAN_B; off <<= 1) {
        int a = (t >= off) ? sh[t - off] : 0;
        __syncthreads();
        sh[t] += a;
        __syncthreads();
    }
    if (i < NN) rowptr[i] = sh[t] - v;          // exclusive
    if (t == SCAN_B - 1) bsums[blockIdx.x] = sh[t];
}

__global__ __launch_bounds__(128) void scan2_kernel(int* bsums) {
    __shared__ int sh[128];
    int t = threadIdx.x;
    int v = (t < NB1) ? bsums[t] : 0;
    sh[t] = v;
    __syncthreads();
    for (int off = 1; off < 128; off <<= 1) {
        int a = (t >= off) ? sh[t - off] : 0;
        __syncthreads();
        sh[t] += a;
        __syncthreads();
    }
    if (t < NB1) bsums[t] = sh[t] - v;          // exclusive
}

__global__ __launch_bounds__(SCAN_B) void scan3_kernel(int* __restrict__ rowptr,
                                                       const int* __restrict__ bsums,
                                                       int* __restrict__ cursor) {
    int i = blockIdx.x * SCAN_B + threadIdx.x;
    if (i < NN) {
        int r = rowptr[i] + bsums[i >> 10];
        rowptr[i] = r;
        cursor[i] = r;
    }
    if (i == 0) rowptr[NN] = NE;
}

__global__ __launch_bounds__(256) void fill_kernel(const void* ei, const int* flag,
                                                   int* cursor, int* esrc) {
    int e = blockIdx.x * 256 + threadIdx.x;
    if (e >= NE) return;
    int i64f = *flag;
    int s = edge_at(ei, i64f, e);
    int d = edge_at(ei, i64f, (long long)NE + e);
    int pos = atomicAdd(&cursor[d], 1);
    esrc[pos] = s;
}

// ---------------- aggregation + fused MLP ----------------
// y2 = (relu(y1 + A y1 + b1a)) @ Wc + bc1      (Wc = w1b@w2a, bc1 = b1b@w2a)
__global__ __launch_bounds__(256) void agg_mlp1_kernel(const float* __restrict__ y1,
                                                       const int* __restrict__ rowptr,
                                                       const int* __restrict__ esrc,
                                                       const float* __restrict__ b1a,
                                                       const float* __restrict__ Wc,
                                                       const float* __restrict__ bc1,
                                                       float* __restrict__ y2) {
    __shared__ float Wl[HID * HID];
    __shared__ float bcl[HID];
    __shared__ float b1l[HID];
    int t = threadIdx.x;
    #pragma unroll
    for (int i = 0; i < 4; i++) Wl[i * 256 + t] = Wc[i * 256 + t];
    if (t < HID) { bcl[t] = bc1[t]; b1l[t] = b1a[t]; }
    __syncthreads();

    int n = blockIdx.x * 8 + (t >> 5);
    int f = t & 31;
    float v = y1[n * HID + f];
    int beg = rowptr[n], end = rowptr[n + 1];
    for (int p = beg; p < end; p++) {
        int s = esrc[p];
        v += y1[s * HID + f];
    }
    v += b1l[f];
    v = v > 0.f ? v : 0.f;
    float acc = 0.f;
    #pragma unroll
    for (int k = 0; k < HID; k++) {
        float uk = __shfl(v, k, 32);
        acc += uk * Wl[k * HID + f];
    }
    y2[n * HID + f] = acc + bcl[f];
}

// s = relu(y2 + A y2 + b2a) . wc2 + c0          (wc2 = w2b@w3, c0 = b2b@w3)
__global__ __launch_bounds__(256) void agg_mlp2_kernel(const float* __restrict__ y2,
                                                       const int* __restrict__ rowptr,
                                                       const int* __restrict__ esrc,
                                                       const float* __restrict__ b2a,
                                                       const float* __restrict__ wc2,
                                                       const float* __restrict__ c0,
                                                       float* __restrict__ sbuf) {
    __shared__ float wcl[HID];
    __shared__ float b2l[HID];
    int t = threadIdx.x;
    if (t < HID) { wcl[t] = wc2[t]; b2l[t] = b2a[t]; }
    __syncthreads();

    int n = blockIdx.x * 8 + (t >> 5);
    int f = t & 31;
    float v = y2[n * HID + f];
    int beg = rowptr[n], end = rowptr[n + 1];
    for (int p = beg; p < end; p++) {
        int s = esrc[p];
        v += y2[s * HID + f];
    }
    v += b2l[f];
    v = v > 0.f ? v : 0.f;
    float tt = v * wcl[f];
    #pragma unroll
    for (int off = 16; off > 0; off >>= 1) tt += __shfl_xor(tt, off, 32);
    if (f == 0) sbuf[n] = tt + *c0;
}

// out = s + A s + b3   (scalar aggregation)
__global__ __launch_bounds__(256) void final_kernel(const float* __restrict__ sbuf,
                                                    const int* __restrict__ rowptr,
                                                    const int* __restrict__ esrc,
                                                    const float* __restrict__ b3,
                                                    float* __restrict__ out) {
    int n = blockIdx.x * 256 + threadIdx.x;
    if (n >= NN) return;
    float v = sbuf[n] + b3[0];
    int beg = rowptr[n], end = rowptr[n + 1];
    for (int p = beg; p < end; p++) v += sbuf[esrc[p]];
    out[n] = v;
}

// ---------------- host ----------------
extern "C" void kernel_launch(void* const* d_in, const int* in_sizes, int n_in,
                              void* d_out, int out_size, void* d_ws, size_t ws_size,
                              hipStream_t stream) {
    const float* x   = (const float*)d_in[0];
    const void*  ei  = d_in[1];
    const float* w1a = (const float*)d_in[2];
    const float* b1a = (const float*)d_in[3];
    const float* w1b = (const float*)d_in[4];
    const float* b1b = (const float*)d_in[5];
    const float* w2a = (const float*)d_in[6];
    const float* b2a = (const float*)d_in[7];
    const float* w2b = (const float*)d_in[8];
    const float* b2b = (const float*)d_in[9];
    const float* w3  = (const float*)d_in[10];
    const float* b3  = (const float*)d_in[11];
    float* out = (float*)d_out;

    char* w = (char*)d_ws;
    float* y1     = (float*)(w + 0);           // 12,800,000 B
    float* y2     = (float*)(w + 12800000);    // 12,800,000 B
    float* sbuf   = (float*)(w + 25600000);    //    400,000 B
    int*   rowptr = (int*)  (w + 26000000);    //    400,016 B (N+1 padded)
    int*   cursor = (int*)  (w + 26400016);    //    400,000 B
    int*   esrc   = (int*)  (w + 26800016);    //  6,400,000 B
    int*   bsums  = (int*)  (w + 33200016);    //        512 B
    int*   flag   = (int*)  (w + 33200528);    //         16 B
    float* Wc     = (float*)(w + 33200544);    //      4,096 B
    float* bc1    = (float*)(w + 33204640);    //        128 B
    float* wc2    = (float*)(w + 33204768);    //        128 B
    float* c0     = (float*)(w + 33204896);    //         16 B

    detect_kernel<<<1, 1, 0, stream>>>(ei, flag);
    zero_kernel<<<(NN + 255) / 256, 256, 0, stream>>>(cursor, NN);
    precompute_kernel<<<1, 1024, 0, stream>>>(w1b, b1b, w2a, w2b, b2b, w3, Wc, bc1, wc2, c0);
    proj1_kernel<<<(NN + 63) / 64, 256, 0, stream>>>(x, w1a, y1);

    count_kernel<<<NE / 256, 256, 0, stream>>>(ei, flag, cursor);
    scan1_kernel<<<NB1, SCAN_B, 0, stream>>>(cursor, rowptr, bsums);
    scan2_kernel<<<1, 128, 0, stream>>>(bsums);
    scan3_kernel<<<NB1, SCAN_B, 0, stream>>>(rowptr, bsums, cursor);
    fill_kernel<<<NE / 256, 256, 0, stream>>>(ei, flag, cursor, esrc);

    agg_mlp1_kernel<<<NN / 8, 256, 0, stream>>>(y1, rowptr, esrc, b1a, Wc, bc1, y2);
    agg_mlp2_kernel<<<NN / 8, 256, 0, stream>>>(y2, rowptr, esrc, b2a, wc2, c0, sbuf);
    final_kernel<<<(NN + 255) / 256, 256, 0, stream>>>(sbuf, rowptr, esrc, b3, out);
}